// Round 10
// baseline (444.954 us; speedup 1.0000x reference)
//
#include <hip/hip_runtime.h>
#include <hip/hip_bf16.h>

#define GRID 512

typedef __attribute__((ext_vector_type(8))) short bf16x8;
typedef __attribute__((ext_vector_type(4))) float f32x4;
typedef __attribute__((ext_vector_type(8))) unsigned short u16x8;

__device__ __forceinline__ void gload16(const void* g, void* l) {
    __builtin_amdgcn_global_load_lds((const __attribute__((address_space(1))) void*)g,
                                     (__attribute__((address_space(3))) void*)l, 16, 0, 0);
}
__device__ __forceinline__ float bf2f(unsigned short u) {
    union { unsigned i; float f; } v; v.i = ((unsigned)u) << 16; return v.f;
}
__device__ __forceinline__ unsigned short f2bf(float f) {
    __hip_bfloat16 h = __float2bfloat16(f);
    return *(unsigned short*)&h;
}

// ---------------------------------------------------------------------------
// conv_chunk: one 8-elem fp32->bf16 zero-padded conversion chunk.
// ---------------------------------------------------------------------------
__device__ __forceinline__ void conv_chunk(
    const float* __restrict__ src, int ld, int col0, int M, int K, int Kp,
    unsigned short* __restrict__ dst, int cid)
{
    const int kp8 = Kp >> 3;
    const int m = cid / kp8;
    const int kc = (cid - m * kp8) << 3;
    u16x8 v;
    if (m < M && kc + 8 <= K) {
        const float* s = src + (size_t)m * ld + col0 + kc;
        const float4 f0 = *(const float4*)s;
        const float4 f1 = *(const float4*)(s + 4);
        const float ff[8] = {f0.x, f0.y, f0.z, f0.w, f1.x, f1.y, f1.z, f1.w};
        #pragma unroll
        for (int j = 0; j < 8; ++j) v[j] = f2bf(ff[j]);
    } else {
        #pragma unroll
        for (int j = 0; j < 8; ++j) {
            float f = 0.f;
            const int k = kc + j;
            if (m < M && k < K) f = src[(size_t)m * ld + col0 + k];
            v[j] = f2bf(f);
        }
    }
    *(u16x8*)(dst + (size_t)m * Kp + kc) = v;
}

// ---------------------------------------------------------------------------
// stage_f32: reg-staged ROWSx64 fp32->bf16 tile into XOR-swizzled LDS (G1).
// ---------------------------------------------------------------------------
template<int ROWS>
__device__ __forceinline__ void stage_f32(
    const float* __restrict__ src, int ld, int row0, int rmax,
    int k0, int kmax, short* __restrict__ lds, int tid)
{
    #pragma unroll
    for (int i = 0; i < ROWS / 32; ++i) {
        const int ch = i * 256 + tid;
        const int r = ch >> 3;
        const int kc8 = (ch & 7) * 8;
        const int gr = row0 + r;
        const int gk = k0 + kc8;
        u16x8 v;
        if (gr < rmax && gk + 8 <= kmax) {
            const float* s = src + (size_t)gr * ld + gk;
            const float4 f0 = *(const float4*)s;
            const float4 f1 = *(const float4*)(s + 4);
            const float ff[8] = {f0.x, f0.y, f0.z, f0.w, f1.x, f1.y, f1.z, f1.w};
            #pragma unroll
            for (int j = 0; j < 8; ++j) v[j] = f2bf(ff[j]);
        } else if (gr < rmax && gk < kmax) {
            #pragma unroll
            for (int j = 0; j < 8; ++j) {
                float f = 0.f;
                if (gk + j < kmax) f = src[(size_t)gr * ld + gk + j];
                v[j] = f2bf(f);
            }
        } else {
            v = (u16x8){0, 0, 0, 0, 0, 0, 0, 0};
        }
        *(u16x8*)((char*)lds + r * 128 + ((kc8 * 2) ^ ((r & 7) << 4))) = v;
    }
}

// ---------------------------------------------------------------------------
// stage_gl: ROWSx64 bf16 tile -> linear LDS via global_load_lds w16,
// source byte-col XOR-pre-swizzled (rule #21 both-sides).
// ---------------------------------------------------------------------------
template<int ROWS>
__device__ __forceinline__ void stage_gl(const unsigned short* __restrict__ src,
                                         int ld, int row0, int k0,
                                         short* __restrict__ lds, int w, int l)
{
    const int sr0 = w * 8 + (l >> 3);
    const int scb = (l & 7) * 16;
    #pragma unroll
    for (int c = 0; c < ROWS / 32; ++c) {
        const int r = c * 32 + sr0;
        const int cbs = scb ^ ((r & 7) << 4);
        const char* g = (const char*)(src + (size_t)(row0 + r) * ld + k0) + cbs;
        char* dst = (char*)lds + (size_t)(c * 32 + w * 8) * 128;
        gload16(g, dst);
    }
}

// ---------------------------------------------------------------------------
// 64x64 GEMM body (relu+bias, bf16 out) — G2.
// ---------------------------------------------------------------------------
__device__ __forceinline__ void gemm64_body(
    const unsigned short* __restrict__ A, const unsigned short* __restrict__ B,
    const float* __restrict__ bias, unsigned short* __restrict__ Cout, int ldc,
    int bm, int bn, int Kp, int Mtrue,
    short* As, short* Bs, int tid)
{
    const int w = tid >> 6, l = tid & 63;
    const int wm = w >> 1, wn = w & 1;
    f32x4 acc[2][2];
    #pragma unroll
    for (int i = 0; i < 2; ++i)
        #pragma unroll
        for (int j = 0; j < 2; ++j)
            acc[i][j] = (f32x4){0.f, 0.f, 0.f, 0.f};

    for (int k0 = 0; k0 < Kp; k0 += 64) {
        stage_gl<64>(A, Kp, bm, k0, As, w, l);
        stage_gl<64>(B, Kp, bn, k0, Bs, w, l);
        asm volatile("s_waitcnt vmcnt(0)");
        __syncthreads();
        #pragma unroll
        for (int ks = 0; ks < 64; ks += 32) {
            bf16x8 a[2], b[2];
            const int kb = ks * 2 + (l >> 4) * 16;
            #pragma unroll
            for (int i = 0; i < 2; ++i) {
                const int ra = wm * 32 + i * 16 + (l & 15);
                a[i] = *(const bf16x8*)((const char*)As + ra * 128 + (kb ^ ((ra & 7) << 4)));
                const int rb = wn * 32 + i * 16 + (l & 15);
                b[i] = *(const bf16x8*)((const char*)Bs + rb * 128 + (kb ^ ((rb & 7) << 4)));
            }
            #pragma unroll
            for (int i = 0; i < 2; ++i)
                #pragma unroll
                for (int j = 0; j < 2; ++j)
                    acc[i][j] = __builtin_amdgcn_mfma_f32_16x16x32_bf16(a[i], b[j], acc[i][j], 0, 0, 0);
        }
        __syncthreads();
    }

    #pragma unroll
    for (int i = 0; i < 2; ++i) {
        #pragma unroll
        for (int j = 0; j < 2; ++j) {
            const int col = bn + wn * 32 + j * 16 + (l & 15);
            const float bv = bias[col];
            #pragma unroll
            for (int q = 0; q < 4; ++q) {
                const int row = bm + wm * 32 + i * 16 + (l >> 4) * 4 + q;
                float v = fmaxf(acc[i][j][q] + bv, 0.f);
                if (row >= Mtrue) v = 0.f;
                Cout[(size_t)row * ldc + col] = f2bf(v);
            }
        }
    }
}

// ---------------------------------------------------------------------------
// 128x128 split-K GEMM body, fp32 slab stores.
// ---------------------------------------------------------------------------
__device__ __forceinline__ void gemm128_body(
    const unsigned short* __restrict__ A, const unsigned short* __restrict__ B,
    float* __restrict__ slab, int by, int bx, int k_begin, int k_steps, int Mtrue,
    short* As, short* Bs, int tid)
{
    const int w = tid >> 6, l = tid & 63;
    const int wm = w >> 1, wn = w & 1;
    f32x4 acc[4][4];
    #pragma unroll
    for (int i = 0; i < 4; ++i)
        #pragma unroll
        for (int j = 0; j < 4; ++j)
            acc[i][j] = (f32x4){0.f, 0.f, 0.f, 0.f};

    for (int t = 0; t < k_steps; ++t) {
        const int k0 = k_begin + t * 64;
        stage_gl<128>(A, 4096, by * 128, k0, As, w, l);
        stage_gl<128>(B, 4096, bx * 128, k0, Bs, w, l);
        asm volatile("s_waitcnt vmcnt(0)");
        __syncthreads();
        #pragma unroll
        for (int ks = 0; ks < 64; ks += 32) {
            bf16x8 a[4], b[4];
            const int kb = ks * 2 + (l >> 4) * 16;
            #pragma unroll
            for (int i = 0; i < 4; ++i) {
                const int ra = wm * 64 + i * 16 + (l & 15);
                a[i] = *(const bf16x8*)((const char*)As + ra * 128 + (kb ^ ((ra & 7) << 4)));
                const int rb = wn * 64 + i * 16 + (l & 15);
                b[i] = *(const bf16x8*)((const char*)Bs + rb * 128 + (kb ^ ((rb & 7) << 4)));
            }
            #pragma unroll
            for (int i = 0; i < 4; ++i)
                #pragma unroll
                for (int j = 0; j < 4; ++j)
                    acc[i][j] = __builtin_amdgcn_mfma_f32_16x16x32_bf16(a[i], b[j], acc[i][j], 0, 0, 0);
        }
        __syncthreads();
    }

    #pragma unroll
    for (int i = 0; i < 4; ++i) {
        #pragma unroll
        for (int j = 0; j < 4; ++j) {
            const int col = bx * 128 + wn * 64 + j * 16 + (l & 15);
            if (col >= 900) continue;
            #pragma unroll
            for (int q = 0; q < 4; ++q) {
                const int row = by * 128 + wm * 64 + i * 16 + (l >> 4) * 4 + q;
                if (row < Mtrue)
                    slab[(size_t)row * 900 + col] = acc[i][j][q];
            }
        }
    }
}

// ---------------------------------------------------------------------------
// slab reduce: o[m][0..903] = bf16( sum over NS slabs (+bias) )
// ---------------------------------------------------------------------------
template<int NS>
__device__ __forceinline__ void reduceNS(const float* __restrict__ p,
                                         const float* __restrict__ bias,
                                         unsigned short* __restrict__ o,
                                         int M, int idx)
{
    const int m = idx / 113;
    const int c = idx - m * 113;
    const int k = c * 8;
    u16x8 v;
    #pragma unroll
    for (int q = 0; q < 8; q += 4) {
        if (k + q < 900) {
            float4 a = *(const float4*)(p + (size_t)m * 900 + k + q);
            #pragma unroll 1
            for (int s = 1; s < NS; ++s) {
                const float4 t = *(const float4*)(p + ((size_t)s * M + m) * 900 + k + q);
                a.x += t.x; a.y += t.y; a.z += t.z; a.w += t.w;
            }
            if (bias) {
                const float4 bb = *(const float4*)(bias + k + q);
                a.x += bb.x; a.y += bb.y; a.z += bb.z; a.w += bb.w;
            }
            v[q + 0] = f2bf(a.x); v[q + 1] = f2bf(a.y);
            v[q + 2] = f2bf(a.z); v[q + 3] = f2bf(a.w);
        } else {
            #pragma unroll
            for (int j = 0; j < 4; ++j) v[q + j] = 0;
        }
    }
    *(u16x8*)(o + (size_t)m * 904 + k) = v;
}

// ---------------------------------------------------------------------------
// Grid barrier: counter k; last arriver resets counter k-1 (safe: all blocks
// passed k-1's spin before any block can complete barrier k).
// ---------------------------------------------------------------------------
__device__ __forceinline__ void gbar(unsigned* __restrict__ c, int k)
{
    __syncthreads();
    if (threadIdx.x == 0) {
        __threadfence();
        const unsigned old = __hip_atomic_fetch_add(&c[k], 1u, __ATOMIC_ACQ_REL,
                                                    __HIP_MEMORY_SCOPE_AGENT);
        if (old == GRID - 1 && k > 0)
            __hip_atomic_store(&c[k - 1], 0u, __ATOMIC_RELAXED, __HIP_MEMORY_SCOPE_AGENT);
        while (__hip_atomic_load(&c[k], __ATOMIC_ACQUIRE, __HIP_MEMORY_SCOPE_AGENT)
               < (unsigned)GRID)
            __builtin_amdgcn_s_sleep(2);
        __threadfence();
    }
    __syncthreads();
}

// ---------------------------------------------------------------------------
union SMem {
    struct { short As[128 * 64]; short Bs[128 * 64]; } g;             // 32 KB
    struct { unsigned short hxs[4 * 904]; unsigned short has[16 * 904];
             float w4s[904]; float zpart[4][4][16]; } s;              // ~43 KB
};

struct MArgs {
    const float *x, *att, *W1, *b1, *b2, *W2, *W3, *b3, *W4, *b4;
    const int *xl, *al;
    unsigned short *x_bf, *W2_bf, *W3x_bf, *W3a_bf, *h1, *attf, *hx_bf, *ha_bf;
    float *hxp, *hap, *out;
    unsigned* cnt;
};

__global__ __launch_bounds__(256)
void mega(MArgs a)
{
    __shared__ SMem sm;
    const int bid = blockIdx.x;
    const int tid = threadIdx.x;

    // ================= P0: conversions + G1 =================
    if (bid < 60) {
        const int bm = (bid & 3) * 64, bn = (bid >> 2) * 64;
        const int w = tid >> 6, l = tid & 63;
        const int wm = w >> 1, wn = w & 1;
        f32x4 acc[2][2];
        #pragma unroll
        for (int i = 0; i < 2; ++i)
            #pragma unroll
            for (int j = 0; j < 2; ++j)
                acc[i][j] = (f32x4){0.f, 0.f, 0.f, 0.f};

        for (int k0 = 0; k0 < 320; k0 += 64) {
            stage_f32<64>(a.att, 312, bm, 200, k0, 312, sm.g.As, tid);
            stage_f32<64>(a.W1,  312, bn, 900, k0, 312, sm.g.Bs, tid);
            __syncthreads();
            #pragma unroll
            for (int ks = 0; ks < 64; ks += 32) {
                bf16x8 av[2], bv[2];
                const int kb = ks * 2 + (l >> 4) * 16;
                #pragma unroll
                for (int i = 0; i < 2; ++i) {
                    const int ra = wm * 32 + i * 16 + (l & 15);
                    av[i] = *(const bf16x8*)((const char*)sm.g.As + ra * 128 + (kb ^ ((ra & 7) << 4)));
                    const int rb = wn * 32 + i * 16 + (l & 15);
                    bv[i] = *(const bf16x8*)((const char*)sm.g.Bs + rb * 128 + (kb ^ ((rb & 7) << 4)));
                }
                #pragma unroll
                for (int i = 0; i < 2; ++i)
                    #pragma unroll
                    for (int j = 0; j < 2; ++j)
                        acc[i][j] = __builtin_amdgcn_mfma_f32_16x16x32_bf16(av[i], bv[j], acc[i][j], 0, 0, 0);
            }
            __syncthreads();
        }
        #pragma unroll
        for (int i = 0; i < 2; ++i) {
            #pragma unroll
            for (int j = 0; j < 2; ++j) {
                const int col = bn + wn * 32 + j * 16 + (l & 15);
                const float bvv = (col < 900) ? a.b1[col] : 0.f;
                #pragma unroll
                for (int q = 0; q < 4; ++q) {
                    const int row = bm + wm * 32 + i * 16 + (l >> 4) * 4 + q;
                    float v = fmaxf(acc[i][j][q] + bvv, 0.f);
                    if (row >= 200) v = 0.f;
                    a.h1[(size_t)row * 960 + col] = f2bf(v);
                }
            }
        }
    } else {
        for (int idx = (bid - 60) * 256 + tid; idx < 1802240; idx += 452 * 256) {
            if (idx < 262144)       conv_chunk(a.x,  4096,    0,  512, 4096, 4096, a.x_bf,   idx);
            else if (idx < 753664)  conv_chunk(a.W2,  900,    0, 4096,  900,  960, a.W2_bf,  idx - 262144);
            else if (idx < 1277952) conv_chunk(a.W3, 8192,    0,  900, 4096, 4096, a.W3x_bf, idx - 753664);
            else                    conv_chunk(a.W3, 8192, 4096,  900, 4096, 4096, a.W3a_bf, idx - 1277952);
        }
        if (bid == 60 && tid == 0) a.out[0] = 0.f;
    }
    gbar(a.cnt, 0);

    // ================= P1: G2 + G3 (split-8) =================
    if (bid < 256) {
        gemm64_body(a.h1, a.W2_bf, a.b2, a.attf, 4096,
                    (bid >> 6) * 64, (bid & 63) * 64, 960, 200, sm.g.As, sm.g.Bs, tid);
    } else {
        const int g = bid - 256;
        const int z = g >> 5, by = (g >> 3) & 3, bx = g & 7;
        gemm128_body(a.x_bf, a.W3x_bf, a.hxp + (size_t)z * 512 * 900,
                     by, bx, z * 512, 8, 512, sm.g.As, sm.g.Bs, tid);
    }
    gbar(a.cnt, 1);

    // ================= P2: G4 (split-16) + reduce hx =================
    if (bid < 256) {
        const int z = bid >> 4, by = (bid >> 3) & 1, bx = bid & 7;
        gemm128_body(a.attf, a.W3a_bf, a.hap + (size_t)z * 200 * 900,
                     by, bx, z * 256, 4, 200, sm.g.As, sm.g.Bs, tid);
    } else {
        const int idx = (bid - 256) * 256 + tid;
        if (idx < 57856) reduceNS<8>(a.hxp, a.b3, a.hx_bf, 512, idx);
    }
    gbar(a.cnt, 2);

    // ================= P3: reduce ha =================
    {
        const int idx = bid * 256 + tid;
        if (idx < 22600) reduceNS<16>(a.hap, nullptr, a.ha_bf, 200, idx);
    }
    gbar(a.cnt, 3);

    // ================= P4: score =================
    {
        const int b = bid >> 7, st4 = (bid >> 2) & 31, nt = bid & 3;
        const int row0 = b * 128 + st4 * 4;

        for (int t = tid; t < 2260; t += 256) {
            u16x8 v;
            unsigned short* dst;
            if (t < 452) {
                const int r = t / 113, c = t - r * 113;
                v = *(const u16x8*)(a.hx_bf + (size_t)(row0 + r) * 904 + c * 8);
                dst = sm.s.hxs + r * 904 + c * 8;
            } else {
                const int t2 = t - 452;
                const int r = t2 / 113, c = t2 - r * 113;
                const int n = nt * 16 + r;
                if (n < 50) v = *(const u16x8*)(a.ha_bf + (size_t)(b * 50 + n) * 904 + c * 8);
                else        v = (u16x8){0, 0, 0, 0, 0, 0, 0, 0};
                dst = sm.s.has + r * 904 + c * 8;
            }
            *(u16x8*)dst = v;
        }
        for (int t = tid; t < 226; t += 256) {
            float4 v = {0.f, 0.f, 0.f, 0.f};
            if (t < 225) v = *(const float4*)(a.W4 + t * 4);
            *(float4*)(sm.s.w4s + t * 4) = v;
        }
        __syncthreads();

        const int hs = tid >> 6, si = (tid >> 4) & 3, ni = tid & 15;
        float acc = 0.f;
        const unsigned short* hrow = sm.s.hxs + si * 904;
        const unsigned short* arow = sm.s.has + ni * 904;
        for (int c = hs; c < 113; c += 4) {
            const u16x8 hv = *(const u16x8*)(hrow + c * 8);
            const u16x8 av = *(const u16x8*)(arow + c * 8);
            const float4 w0 = *(const float4*)(sm.s.w4s + c * 8);
            const float4 w1 = *(const float4*)(sm.s.w4s + c * 8 + 4);
            const float ww[8] = {w0.x, w0.y, w0.z, w0.w, w1.x, w1.y, w1.z, w1.w};
            #pragma unroll
            for (int j = 0; j < 8; ++j) {
                const float u = bf2f((unsigned short)hv[j]) + bf2f((unsigned short)av[j]);
                acc = fmaf(fmaxf(u, 0.f), ww[j], acc);
            }
        }
        sm.s.zpart[hs][si][ni] = acc;
        __syncthreads();

        if (tid < 64) {
            const int esi = tid >> 4, eni = tid & 15;
            const int n = nt * 16 + eni;
            const float z = sm.s.zpart[0][esi][eni] + sm.s.zpart[1][esi][eni]
                          + sm.s.zpart[2][esi][eni] + sm.s.zpart[3][esi][eni] + a.b4[0];
            const float sc = 1.f / (1.f + __expf(-z));
            float dd = 0.f;
            if (n < 50) {
                const float lab = (a.xl[row0 + esi] == a.al[b * 50 + n]) ? 1.f : 0.f;
                const float d = lab - sc;
                dd = d * d;
            }
            #pragma unroll
            for (int off = 32; off > 0; off >>= 1)
                dd += __shfl_down(dd, off);
            if (tid == 0) atomicAdd(a.out, dd * (1.f / 512.f));
        }
    }

    // exit counter: last block resets c[3] and c[4] (all blocks past c[3] here)
    __syncthreads();
    if (tid == 0) {
        const unsigned old = __hip_atomic_fetch_add(&a.cnt[4], 1u, __ATOMIC_ACQ_REL,
                                                    __HIP_MEMORY_SCOPE_AGENT);
        if (old == GRID - 1) {
            __hip_atomic_store(&a.cnt[3], 0u, __ATOMIC_RELAXED, __HIP_MEMORY_SCOPE_AGENT);
            __hip_atomic_store(&a.cnt[4], 0u, __ATOMIC_RELAXED, __HIP_MEMORY_SCOPE_AGENT);
        }
    }
}

// Zero the barrier counters (ws is poisoned 0xAA before timing; counters must
// start at 0 every call). Kernel node, NOT hipMemsetAsync (tiny fill nodes
// showed ~39us in R3's trace).
__global__ void bz(unsigned* c)
{
    if (threadIdx.x < 8) c[threadIdx.x] = 0;
}

extern "C" void kernel_launch(void* const* d_in, const int* in_sizes, int n_in,
                              void* d_out, int out_size, void* d_ws, size_t ws_size,
                              hipStream_t stream)
{
    const float* x   = (const float*)d_in[0];
    const int*   xl  = (const int*)  d_in[1];
    const float* att = (const float*)d_in[2];
    const int*   al  = (const int*)  d_in[3];
    const float* W1  = (const float*)d_in[4];
    const float* b1  = (const float*)d_in[5];
    const float* W2  = (const float*)d_in[6];
    const float* b2  = (const float*)d_in[7];
    const float* W3  = (const float*)d_in[8];
    const float* b3  = (const float*)d_in[9];
    const float* W4  = (const float*)d_in[10];
    const float* b4  = (const float*)d_in[11];
    float* out = (float*)d_out;

    const int MS = 512, C = 4096, Hp = 960, MNp = 256, W3p = 1024;

    char* base = (char*)d_ws;
    size_t off = 0;
    auto alloc = [&](size_t bytes) { void* r = base + off; off = (off + bytes + 255) & ~(size_t)255; return r; };
    unsigned short* x_bf   = (unsigned short*)alloc((size_t)MS * C * 2);
    unsigned short* W2_bf  = (unsigned short*)alloc((size_t)C * Hp * 2);
    unsigned short* W3x_bf = (unsigned short*)alloc((size_t)W3p * C * 2);
    unsigned short* W3a_bf = (unsigned short*)alloc((size_t)W3p * C * 2);
    unsigned short* h1_bf  = (unsigned short*)alloc((size_t)MNp * Hp * 2);
    unsigned short* attf_bf= (unsigned short*)alloc((size_t)MNp * C * 2);
    float* hxp = (float*)alloc((size_t)8 * 512 * 900 * 4);
    float* hap = (float*)alloc((size_t)16 * 200 * 900 * 4);
    unsigned short* hx_bf = (unsigned short*)alloc((size_t)512 * 904 * 2);
    unsigned short* ha_bf = (unsigned short*)alloc((size_t)200 * 904 * 2);
    unsigned* cnt = (unsigned*)alloc(64);

    bz<<<dim3(1), dim3(64), 0, stream>>>(cnt);

    MArgs A;
    A.x = x; A.att = att; A.W1 = W1; A.b1 = b1; A.b2 = b2; A.W2 = W2; A.W3 = W3;
    A.b3 = b3; A.W4 = W4; A.b4 = b4; A.xl = xl; A.al = al;
    A.x_bf = x_bf; A.W2_bf = W2_bf; A.W3x_bf = W3x_bf; A.W3a_bf = W3a_bf;
    A.h1 = h1_bf; A.attf = attf_bf; A.hx_bf = hx_bf; A.ha_bf = ha_bf;
    A.hxp = hxp; A.hap = hap; A.out = out; A.cnt = cnt;

    mega<<<dim3(GRID), dim3(256), 0, stream>>>(A);
}

// Round 11
// 68.962 us; speedup vs baseline: 6.4522x; 6.4522x over previous
//
#include <hip/hip_runtime.h>
#include <hip/hip_bf16.h>

typedef __attribute__((ext_vector_type(8))) short bf16x8;
typedef __attribute__((ext_vector_type(4))) float f32x4;
typedef __attribute__((ext_vector_type(8))) unsigned short u16x8;

__device__ __forceinline__ void gload16(const void* g, void* l) {
    __builtin_amdgcn_global_load_lds((const __attribute__((address_space(1))) void*)g,
                                     (__attribute__((address_space(3))) void*)l, 16, 0, 0);
}
__device__ __forceinline__ float bf2f(unsigned short u) {
    union { unsigned i; float f; } v; v.i = ((unsigned)u) << 16; return v.f;
}
__device__ __forceinline__ unsigned short f2bf(float f) {
    __hip_bfloat16 h = __float2bfloat16(f);
    return *(unsigned short*)&h;
}

// ---------------------------------------------------------------------------
// stage_f32: reg-staged ROWSx64 fp32->bf16 tile into XOR-swizzled LDS (G1).
// ---------------------------------------------------------------------------
template<int ROWS>
__device__ __forceinline__ void stage_f32(
    const float* __restrict__ src, int ld, int row0, int rmax,
    int k0, int kmax, short* __restrict__ lds, int tid)
{
    #pragma unroll
    for (int i = 0; i < ROWS / 32; ++i) {
        const int ch = i * 256 + tid;
        const int r = ch >> 3;
        const int kc8 = (ch & 7) * 8;
        const int gr = row0 + r;
        const int gk = k0 + kc8;
        u16x8 v;
        if (gr < rmax && gk + 8 <= kmax) {
            const float* s = src + (size_t)gr * ld + gk;
            const float4 f0 = *(const float4*)s;
            const float4 f1 = *(const float4*)(s + 4);
            const float ff[8] = {f0.x, f0.y, f0.z, f0.w, f1.x, f1.y, f1.z, f1.w};
            #pragma unroll
            for (int j = 0; j < 8; ++j) v[j] = f2bf(ff[j]);
        } else if (gr < rmax && gk < kmax) {
            #pragma unroll
            for (int j = 0; j < 8; ++j) {
                float f = 0.f;
                if (gk + j < kmax) f = src[(size_t)gr * ld + gk + j];
                v[j] = f2bf(f);
            }
        } else {
            v = (u16x8){0, 0, 0, 0, 0, 0, 0, 0};
        }
        *(u16x8*)((char*)lds + r * 128 + ((kc8 * 2) ^ ((r & 7) << 4))) = v;
    }
}

// ---------------------------------------------------------------------------
// stage_gl: ROWSx64 bf16 tile -> linear LDS via global_load_lds w16,
// source byte-col XOR-pre-swizzled (rule #21 both-sides).
// ---------------------------------------------------------------------------
template<int ROWS>
__device__ __forceinline__ void stage_gl(const unsigned short* __restrict__ src,
                                         int ld, int row0, int k0,
                                         short* __restrict__ lds, int w, int l)
{
    const int sr0 = w * 8 + (l >> 3);
    const int scb = (l & 7) * 16;
    #pragma unroll
    for (int c = 0; c < ROWS / 32; ++c) {
        const int r = c * 32 + sr0;
        const int cbs = scb ^ ((r & 7) << 4);
        const char* g = (const char*)(src + (size_t)(row0 + r) * ld + k0) + cbs;
        char* dst = (char*)lds + (size_t)(c * 32 + w * 8) * 128;
        gload16(g, dst);
    }
}

// ---------------------------------------------------------------------------
// padg1: blocks [0,60) = G1 (fp32-staged); blocks [60,..) = 4 pad conversions.
// Block 60 tid 0 also zeroes the output accumulator.
// ---------------------------------------------------------------------------
struct PadJob {
    const float* src; unsigned short* dst;
    int src_ld, col0, M, K, Kp;
    int chunk_begin;
};
struct PG1Args {
    PadJob j[4]; int total;
    const float *att, *W1, *b1;
    unsigned short* h1;
    float* out;
};

__global__ __launch_bounds__(256)
void padg1(PG1Args P)
{
    __shared__ short As[64 * 64];
    __shared__ short Bs[64 * 64];
    const int gid = blockIdx.x;
    const int tid = threadIdx.x;

    if (gid < 60) {
        const int bm = (gid & 3) * 64, bn = (gid >> 2) * 64;
        const int w = tid >> 6, l = tid & 63;
        const int wm = w >> 1, wn = w & 1;

        f32x4 acc[2][2];
        #pragma unroll
        for (int i = 0; i < 2; ++i)
            #pragma unroll
            for (int j = 0; j < 2; ++j)
                acc[i][j] = (f32x4){0.f, 0.f, 0.f, 0.f};

        for (int k0 = 0; k0 < 320; k0 += 64) {
            stage_f32<64>(P.att, 312, bm, 200, k0, 312, As, tid);
            stage_f32<64>(P.W1,  312, bn, 900, k0, 312, Bs, tid);
            __syncthreads();
            #pragma unroll
            for (int ks = 0; ks < 64; ks += 32) {
                bf16x8 a[2], b[2];
                const int kb = ks * 2 + (l >> 4) * 16;
                #pragma unroll
                for (int i = 0; i < 2; ++i) {
                    const int ra = wm * 32 + i * 16 + (l & 15);
                    a[i] = *(const bf16x8*)((const char*)As + ra * 128 + (kb ^ ((ra & 7) << 4)));
                    const int rb = wn * 32 + i * 16 + (l & 15);
                    b[i] = *(const bf16x8*)((const char*)Bs + rb * 128 + (kb ^ ((rb & 7) << 4)));
                }
                #pragma unroll
                for (int i = 0; i < 2; ++i)
                    #pragma unroll
                    for (int j = 0; j < 2; ++j)
                        acc[i][j] = __builtin_amdgcn_mfma_f32_16x16x32_bf16(a[i], b[j], acc[i][j], 0, 0, 0);
            }
            __syncthreads();
        }

        #pragma unroll
        for (int i = 0; i < 2; ++i) {
            #pragma unroll
            for (int j = 0; j < 2; ++j) {
                const int col = bn + wn * 32 + j * 16 + (l & 15);
                const float bv = (col < 900) ? P.b1[col] : 0.f;
                #pragma unroll
                for (int q = 0; q < 4; ++q) {
                    const int row = bm + wm * 32 + i * 16 + (l >> 4) * 4 + q;
                    float v = fmaxf(acc[i][j][q] + bv, 0.f);
                    if (row >= 200) v = 0.f;
                    P.h1[(size_t)row * 960 + col] = f2bf(v);
                }
            }
        }
        return;
    }

    if (gid == 60 && tid == 0) P.out[0] = 0.f;

    const int idx = (gid - 60) * 256 + tid;
    if (idx >= P.total) return;
    int ji = 0;
    #pragma unroll
    for (int k = 1; k < 4; ++k) if (idx >= P.j[k].chunk_begin) ji = k;
    const PadJob J = P.j[ji];
    const int cid = idx - J.chunk_begin;
    const int kp8 = J.Kp >> 3;
    const int m = cid / kp8;
    const int kc = (cid - m * kp8) << 3;
    u16x8 v;
    if (m < J.M && kc + 8 <= J.K) {
        const float* s = J.src + (size_t)m * J.src_ld + J.col0 + kc;
        const float4 f0 = *(const float4*)s;
        const float4 f1 = *(const float4*)(s + 4);
        const float ff[8] = {f0.x, f0.y, f0.z, f0.w, f1.x, f1.y, f1.z, f1.w};
        #pragma unroll
        for (int j = 0; j < 8; ++j) v[j] = f2bf(ff[j]);
    } else {
        #pragma unroll
        for (int j = 0; j < 8; ++j) {
            float f = 0.f;
            const int k = kc + j;
            if (m < J.M && k < J.K) f = J.src[(size_t)m * J.src_ld + J.col0 + k];
            v[j] = f2bf(f);
        }
    }
    *(u16x8*)(J.dst + (size_t)m * J.Kp + kc) = v;
}

// ---------------------------------------------------------------------------
// 64x64 MFMA GEMM (G2), R4 single-buffer structure. bf16 in/out.
// ---------------------------------------------------------------------------
template<bool RELU, bool BIAS>
__global__ __launch_bounds__(256)
void gemm_mfma64(const unsigned short* __restrict__ A,
                 const unsigned short* __restrict__ B,
                 const float* __restrict__ bias,
                 unsigned short* __restrict__ Cout, int ldc,
                 int Mtrue, int Ntrue, int Kp)
{
    __shared__ short As[64 * 64];
    __shared__ short Bs[64 * 64];
    const int bm = blockIdx.y * 64, bn = blockIdx.x * 64;
    const int tid = threadIdx.x;
    const int w = tid >> 6, l = tid & 63;
    const int wm = w >> 1, wn = w & 1;

    f32x4 acc[2][2];
    #pragma unroll
    for (int i = 0; i < 2; ++i)
        #pragma unroll
        for (int j = 0; j < 2; ++j)
            acc[i][j] = (f32x4){0.f, 0.f, 0.f, 0.f};

    for (int k0 = 0; k0 < Kp; k0 += 64) {
        stage_gl<64>(A, Kp, bm, k0, As, w, l);
        stage_gl<64>(B, Kp, bn, k0, Bs, w, l);
        asm volatile("s_waitcnt vmcnt(0)");
        __syncthreads();

        #pragma unroll
        for (int ks = 0; ks < 64; ks += 32) {
            bf16x8 a[2], b[2];
            const int kb = ks * 2 + (l >> 4) * 16;
            #pragma unroll
            for (int i = 0; i < 2; ++i) {
                const int ra = wm * 32 + i * 16 + (l & 15);
                a[i] = *(const bf16x8*)((const char*)As + ra * 128 + (kb ^ ((ra & 7) << 4)));
                const int rb = wn * 32 + i * 16 + (l & 15);
                b[i] = *(const bf16x8*)((const char*)Bs + rb * 128 + (kb ^ ((rb & 7) << 4)));
            }
            #pragma unroll
            for (int i = 0; i < 2; ++i)
                #pragma unroll
                for (int j = 0; j < 2; ++j)
                    acc[i][j] = __builtin_amdgcn_mfma_f32_16x16x32_bf16(a[i], b[j], acc[i][j], 0, 0, 0);
        }
        __syncthreads();
    }

    #pragma unroll
    for (int i = 0; i < 2; ++i) {
        #pragma unroll
        for (int j = 0; j < 2; ++j) {
            const int col = bn + wn * 32 + j * 16 + (l & 15);
            float bv = 0.f;
            if (BIAS && col < Ntrue) bv = bias[col];
            #pragma unroll
            for (int q = 0; q < 4; ++q) {
                const int row = bm + wm * 32 + i * 16 + (l >> 4) * 4 + q;
                float v = acc[i][j][q] + bv;
                if (RELU) v = fmaxf(v, 0.f);
                if (row >= Mtrue) v = 0.f;
                Cout[(size_t)row * ldc + col] = f2bf(v);
            }
        }
    }
}

// ---------------------------------------------------------------------------
// 128x128 split-K GEMM for G3+G4 (R4 structure, single buffer, 384 blocks)
// blocks [0,256): G3  z=gid>>5, by=(gid&31)>>3, bx=gid&7   (split 8, Kc=512)
// blocks [256,384): G4 z=g2>>4, by=(g2&15)>>3,  bx=g2&7    (split 8, Kc=512)
// ---------------------------------------------------------------------------
struct G34Args {
    const unsigned short *A3, *B3; float* P3;
    const unsigned short *A4, *B4; float* P4;
};

__global__ __launch_bounds__(256)
void gemm128_split(G34Args ga)
{
    __shared__ short As[128 * 64];
    __shared__ short Bs[128 * 64];
    const int tid = threadIdx.x;
    const int w = tid >> 6, l = tid & 63;
    const int wm = w >> 1, wn = w & 1;

    const unsigned short *A, *Bm;
    float* P;
    int by, bx, z, Mtrue;
    const int gid = blockIdx.x;
    if (gid < 256) {
        z = gid >> 5; const int rem = gid & 31; by = rem >> 3; bx = rem & 7;
        A = ga.A3; Bm = ga.B3; P = ga.P3; Mtrue = 512;
    } else {
        const int g2 = gid - 256;
        z = g2 >> 4; const int rem = g2 & 15; by = rem >> 3; bx = rem & 7;
        A = ga.A4; Bm = ga.B4; P = ga.P4; Mtrue = 200;
    }
    const int k_begin = z * 512;

    f32x4 acc[4][4];
    #pragma unroll
    for (int i = 0; i < 4; ++i)
        #pragma unroll
        for (int j = 0; j < 4; ++j)
            acc[i][j] = (f32x4){0.f, 0.f, 0.f, 0.f};

    for (int k0 = k_begin; k0 < k_begin + 512; k0 += 64) {
        stage_gl<128>(A, 4096, by * 128, k0, As, w, l);
        stage_gl<128>(Bm, 4096, bx * 128, k0, Bs, w, l);
        asm volatile("s_waitcnt vmcnt(0)");
        __syncthreads();

        #pragma unroll
        for (int ks = 0; ks < 64; ks += 32) {
            bf16x8 a[4], b[4];
            const int kb = ks * 2 + (l >> 4) * 16;
            #pragma unroll
            for (int i = 0; i < 4; ++i) {
                const int ra = wm * 64 + i * 16 + (l & 15);
                a[i] = *(const bf16x8*)((const char*)As + ra * 128 + (kb ^ ((ra & 7) << 4)));
                const int rb = wn * 64 + i * 16 + (l & 15);
                b[i] = *(const bf16x8*)((const char*)Bs + rb * 128 + (kb ^ ((rb & 7) << 4)));
            }
            #pragma unroll
            for (int i = 0; i < 4; ++i)
                #pragma unroll
                for (int j = 0; j < 4; ++j)
                    acc[i][j] = __builtin_amdgcn_mfma_f32_16x16x32_bf16(a[i], b[j], acc[i][j], 0, 0, 0);
        }
        __syncthreads();
    }

    float* slab = P + (size_t)z * Mtrue * 900;
    #pragma unroll
    for (int i = 0; i < 4; ++i) {
        #pragma unroll
        for (int j = 0; j < 4; ++j) {
            const int col = bx * 128 + wn * 64 + j * 16 + (l & 15);
            if (col >= 900) continue;
            #pragma unroll
            for (int q = 0; q < 4; ++q) {
                const int row = by * 128 + wm * 64 + i * 16 + (l >> 4) * 4 + q;
                if (row < Mtrue)
                    slab[(size_t)row * 900 + col] = acc[i][j][q];
            }
        }
    }
}

// ---------------------------------------------------------------------------
// reduce_both: hx = sum of 8 slabs (+b3), ha = sum of 8 slabs -> bf16 [M][904]
// ---------------------------------------------------------------------------
__global__ __launch_bounds__(256)
void reduce_both(const float* __restrict__ hxp, const float* __restrict__ hap,
                 const float* __restrict__ b3,
                 unsigned short* __restrict__ hx_bf, unsigned short* __restrict__ ha_bf)
{
    int idx = blockIdx.x * 256 + threadIdx.x;
    const int HX = 512 * 113;
    const float* p; unsigned short* o; const float* bias; int M;
    if (idx < HX) { p = hxp; o = hx_bf; bias = b3; M = 512; }
    else {
        idx -= HX;
        if (idx >= 200 * 113) return;
        p = hap; o = ha_bf; bias = nullptr; M = 200;
    }
    const int m = idx / 113;
    const int c = idx - m * 113;
    const int k = c * 8;
    u16x8 v;
    #pragma unroll
    for (int q = 0; q < 8; q += 4) {
        if (k + q < 900) {
            float4 a = *(const float4*)(p + (size_t)m * 900 + k + q);
            #pragma unroll 1
            for (int s = 1; s < 8; ++s) {
                const float4 t = *(const float4*)(p + ((size_t)s * M + m) * 900 + k + q);
                a.x += t.x; a.y += t.y; a.z += t.z; a.w += t.w;
            }
            if (bias) {
                const float4 bb = *(const float4*)(bias + k + q);
                a.x += bb.x; a.y += bb.y; a.z += bb.z; a.w += bb.w;
            }
            v[q + 0] = f2bf(a.x); v[q + 1] = f2bf(a.y);
            v[q + 2] = f2bf(a.z); v[q + 3] = f2bf(a.w);
        } else {
            #pragma unroll
            for (int j = 0; j < 4; ++j) v[q + j] = 0;
        }
    }
    *(u16x8*)(o + (size_t)m * 904 + k) = v;
}

// ---------------------------------------------------------------------------
// score/loss (R4 structure): block = 512 thr; grid = (4 nt, 16 st, 4 b)
// One atomicAdd per block into out (zeroed by padg1).
// ---------------------------------------------------------------------------
__global__ __launch_bounds__(512)
void score_loss(const unsigned short* __restrict__ hxb,
                const unsigned short* __restrict__ hab,
                const float* __restrict__ W4,
                const float* __restrict__ b4,
                const int* __restrict__ xl,
                const int* __restrict__ al,
                float* __restrict__ out)
{
    __shared__ __align__(16) unsigned short hxs[8 * 904];
    __shared__ __align__(16) unsigned short has[16 * 904];
    __shared__ __align__(16) float w4s[904];
    __shared__ float zpart[4][8][16];
    __shared__ float red[2];

    const int tid = threadIdx.x;
    const int nt = blockIdx.x, st = blockIdx.y, b = blockIdx.z;
    const int row0 = b * 128 + st * 8;

    for (int t = tid; t < 24 * 113; t += 512) {
        u16x8 v;
        unsigned short* dst;
        if (t < 8 * 113) {
            const int r = t / 113, c = t - r * 113;
            v = *(const u16x8*)(hxb + (size_t)(row0 + r) * 904 + c * 8);
            dst = hxs + r * 904 + c * 8;
        } else {
            const int t2 = t - 8 * 113;
            const int r = t2 / 113, c = t2 - r * 113;
            const int n = nt * 16 + r;
            if (n < 50) v = *(const u16x8*)(hab + (size_t)(b * 50 + n) * 904 + c * 8);
            else        v = (u16x8){0,0,0,0,0,0,0,0};
            dst = has + r * 904 + c * 8;
        }
        *(u16x8*)dst = v;
    }
    for (int t = tid; t < 226; t += 512) {
        float4 v = {0.f, 0.f, 0.f, 0.f};
        if (t < 225) v = *(const float4*)(W4 + t * 4);
        *(float4*)(w4s + t * 4) = v;
    }
    __syncthreads();

    const int hs = tid >> 7;
    const int si = (tid >> 4) & 7;
    const int ni = tid & 15;

    float acc = 0.f;
    const unsigned short* hrow = hxs + si * 904;
    const unsigned short* arow = has + ni * 904;
    for (int c = hs; c < 113; c += 4) {
        const u16x8 hv = *(const u16x8*)(hrow + c * 8);
        const u16x8 av = *(const u16x8*)(arow + c * 8);
        const float4 w0 = *(const float4*)(w4s + c * 8);
        const float4 w1 = *(const float4*)(w4s + c * 8 + 4);
        const float ww[8] = {w0.x, w0.y, w0.z, w0.w, w1.x, w1.y, w1.z, w1.w};
        #pragma unroll
        for (int j = 0; j < 8; ++j) {
            const float u = bf2f((unsigned short)hv[j]) + bf2f((unsigned short)av[j]);
            acc = fmaf(fmaxf(u, 0.f), ww[j], acc);
        }
    }
    zpart[hs][si][ni] = acc;
    __syncthreads();

    float dd = 0.f;
    if (tid < 128) {
        const int esi = tid >> 4, eni = tid & 15;
        const int n = nt * 16 + eni;
        const float z = zpart[0][esi][eni] + zpart[1][esi][eni]
                      + zpart[2][esi][eni] + zpart[3][esi][eni] + b4[0];
        const float sc = 1.f / (1.f + __expf(-z));
        if (n < 50) {
            const float lab = (xl[row0 + esi] == al[b * 50 + n]) ? 1.f : 0.f;
            const float d = lab - sc;
            dd = d * d;
        }
        #pragma unroll
        for (int off = 32; off > 0; off >>= 1)
            dd += __shfl_down(dd, off);
        if ((tid & 63) == 0) red[tid >> 6] = dd;
    }
    __syncthreads();
    if (tid == 0)
        atomicAdd(out, (red[0] + red[1]) * (1.f / 512.f));
}

extern "C" void kernel_launch(void* const* d_in, const int* in_sizes, int n_in,
                              void* d_out, int out_size, void* d_ws, size_t ws_size,
                              hipStream_t stream)
{
    const float* x   = (const float*)d_in[0];
    const int*   xl  = (const int*)  d_in[1];
    const float* att = (const float*)d_in[2];
    const int*   al  = (const int*)  d_in[3];
    const float* W1  = (const float*)d_in[4];
    const float* b1  = (const float*)d_in[5];
    const float* W2  = (const float*)d_in[6];
    const float* b2  = (const float*)d_in[7];
    const float* W3  = (const float*)d_in[8];
    const float* b3  = (const float*)d_in[9];
    const float* W4  = (const float*)d_in[10];
    const float* b4  = (const float*)d_in[11];
    float* out = (float*)d_out;

    const int B = 4, S = 128, N = 50, C = 4096, H = 900, AR = 312;
    const int MS = B * S;            // 512
    const int MN = B * N;            // 200
    const int MNp = 256;
    const int Hp = 960;
    const int W3p = 1024;
    const int SPLITS = 8;

    char* base = (char*)d_ws;
    size_t off = 0;
    auto alloc = [&](size_t bytes) { void* r = base + off; off = (off + bytes + 255) & ~(size_t)255; return r; };
    unsigned short* x_bf   = (unsigned short*)alloc((size_t)MS * C * 2);
    unsigned short* W2_bf  = (unsigned short*)alloc((size_t)C * Hp * 2);
    unsigned short* W3x_bf = (unsigned short*)alloc((size_t)W3p * C * 2);
    unsigned short* W3a_bf = (unsigned short*)alloc((size_t)W3p * C * 2);
    unsigned short* h1_bf  = (unsigned short*)alloc((size_t)MNp * Hp * 2);
    unsigned short* attf_bf= (unsigned short*)alloc((size_t)MNp * C * 2);
    float* hxp = (float*)alloc((size_t)SPLITS * MS * H * 4);
    float* hap = (float*)alloc((size_t)SPLITS * MN * H * 4);
    unsigned short* hx_bf = (unsigned short*)alloc((size_t)MS * 904 * 2);
    unsigned short* ha_bf = (unsigned short*)alloc((size_t)MN * 904 * 2);

    const dim3 blk(256);
    auto cdiv = [](int a, int b) { return (a + b - 1) / b; };

    // ---- launch 1: pad conversions + G1 + zero(out) ----
    PG1Args P;
    int cb = 0;
    auto setjob = [&](int i, const float* src, unsigned short* dst, int ld, int col0,
                      int M, int K, int Kp, int Mp) {
        P.j[i] = PadJob{src, dst, ld, col0, M, K, Kp, cb};
        cb += Mp * (Kp >> 3);
    };
    setjob(0, x,   x_bf,   C,     0, MS, C,  C,   MS);
    setjob(1, W2,  W2_bf,  H,     0, C,  H,  Hp,  C);
    setjob(2, W3,  W3x_bf, 2 * C, 0, H,  C,  C,   W3p);
    setjob(3, W3,  W3a_bf, 2 * C, C, H,  C,  C,   W3p);
    P.total = cb;
    P.att = att; P.W1 = W1; P.b1 = b1; P.h1 = h1_bf; P.out = out;
    padg1<<<dim3(60 + cdiv(cb, 256)), blk, 0, stream>>>(P);

    // ---- launch 2: G2 = relu(h1 @ W2^T + b2) [256][4096], K=960 ----
    gemm_mfma64<true, true><<<dim3(C / 64, MNp / 64), blk, 0, stream>>>(
        h1_bf, W2_bf, b2, attf_bf, C, MN, C, Hp);

    // ---- launch 3: G3+G4 fused, split-K 8, 128^2 tiles ----
    G34Args ga{x_bf, W3x_bf, hxp, attf_bf, W3a_bf, hap};
    gemm128_split<<<dim3(384), blk, 0, stream>>>(ga);

    // ---- launch 4: reduce slabs -> bf16 (b3 folded into hx) ----
    reduce_both<<<cdiv((MS + MN) * 113, 256), blk, 0, stream>>>(hxp, hap, b3, hx_bf, ha_bf);

    // ---- launch 5: score + loss (atomic into out) ----
    score_loss<<<dim3(4, 16, 4), dim3(512), 0, stream>>>(hx_bf, ha_bf, W4, b4, xl, al, out);
}